// Round 18
// baseline (277.626 us; speedup 1.0000x reference)
//
#include <hip/hip_runtime.h>
#include <hip/hip_bf16.h>

// SpatialLinearAttention: b=2,f=16,h=w=64,c=256, heads=8, D=32
// BF=32 fused batch, n=4096, hD=256.
// out[n,c] = sum_hd softmax_d(xWq)[n,hd] * W2[hd,c]
// W2[hd,c] = sum_e (ctx[h,d,e]/den[h,d]) * Wo[h*32+e,c]
// ctx[h,d,e] = sum_n exp(xWk)[n,h*32+d] * (xWv)[n,h*32+e];  den = sum_n exp(xWk)
// r18: fuse q-projection + softmax into k1 (k1q): x is read ONCE; Qs emitted as
//      bf16 (67 MB) instead of k3 re-reading x f32 (134 MB). k3b = pure GEMM
//      Qs @ W2t^T (no softmax, no cvt). Net HBM 427->360 MB; k1's idle MFMA pipe
//      absorbs the extra 50% MFMA; k1q A-ds_reads amortize over 6 MFMAs/kk.

typedef __attribute__((ext_vector_type(8))) short bf16x8;
typedef __attribute__((ext_vector_type(4))) float f32x4;

__device__ __forceinline__ unsigned short f2bf(float x) {
  __hip_bfloat16 h = __float2bfloat16(x);          // HW v_cvt (RNE), 1 VALU op
  union { __hip_bfloat16 b; unsigned short u; } c; c.b = h; return c.u;
}

// LDS-only barrier (r17): fences ds ops, leaves VMEM in flight.
__device__ __forceinline__ void bar_lds() {
  asm volatile("s_waitcnt lgkmcnt(0)" ::: "memory");
  __builtin_amdgcn_s_barrier();
}

// ---------------- K0: transpose & convert weights to [N][K] bf16 ----------------
__global__ __launch_bounds__(256) void k0_prep(const float* __restrict__ Wq,
                                               const float* __restrict__ Wk,
                                               const float* __restrict__ Wv,
                                               unsigned short* __restrict__ WqT,
                                               unsigned short* __restrict__ WkvT) {
  int r = blockIdx.x, c = threadIdx.x;
  if (r < 256)      WqT [(r      )*256 + c] = f2bf(Wq[c*256 + r]);
  else if (r < 512) WkvT[(r - 256)*256 + c] = f2bf(Wk[c*256 + (r-256)]);
  else              WkvT[(r - 256)*256 + c] = f2bf(Wv[c*256 + (r-512)]);
}

// ---------------- K1q: fused kv-proj + exp + ctx + q-proj + softmax ----------------
// Grid 256 x 1024thr (16 waves), 512 rows/block, 16 strips of 32 rows.
// Wave w: 32 cols of [Ek|V] (w<8: Ek head w +exp/den; w>=8: V head w-8)
//         + 16 q-cols [w*16, w*16+16) = head w>>1, half w&1 (pair = w^1).
// Per strip: pre-bar {slabWrite(acc) | q: exp+wave-sum+qsum write | stageA(t+1)}
//            BAR    {q-finish: pair-sum, inv, Qs bf16 global store | prefetch
//                    | ctxMFMA(t) | main+q MFMA(t+1)}
// Slab stride 40 no-XOR. bfr NOT pinned (allocator may remat from L2 under
// pressure -- graceful vs scratch spill; r15 measured remat ~free).
__global__ __launch_bounds__(1024, 4) void k1q(const float* __restrict__ x,
                                               const unsigned short* __restrict__ WkvT,
                                               const unsigned short* __restrict__ WqT,
                                               float* __restrict__ ctxp,
                                               unsigned short* __restrict__ Qs) {
  __shared__ unsigned short As[2][32*256];    // 16 KB each, swizzled (32 slots/row)
  __shared__ unsigned short slab[2][512*40];  // 40 KB each: C^T [c][n], padded
  __shared__ float qsum[2][512];              // 2 KB each: [w][row] wave partial sums
  int bid = blockIdx.x;
  size_t rowbase = (size_t)bid * 512;
  int tid = threadIdx.x;
  int lane = tid & 63, w = tid >> 6;
  int cl = lane & 15, rq = (lane >> 4) << 2, fs = lane >> 4;
  int h = w & 7;
  bool isV = w >= 8;

  // ---- B fragments (kv): rows w*32..+32 of WkvT ----
  bf16x8 bfr[2][8];
#pragma unroll
  for (int ni = 0; ni < 2; ++ni)
#pragma unroll
    for (int kk = 0; kk < 8; ++kk)
      bfr[ni][kk] = *(const bf16x8*)(WkvT + (size_t)(w*32 + ni*16 + cl)*256 + kk*32 + fs*8);

  // q B-panel pointer (loaded per kk inside the MFMA loop, minimal live range)
  const unsigned short* bqp = WqT + (size_t)(w*16 + cl)*256 + fs*8;

  // ---- ctx accumulators: head h, e-half per wave ----
  f32x4 c2[2] = {};
  float dena0 = 0.f, dena1 = 0.f;            // den partials (w<8 only)

  // ---- A staging map: 1024 thr = 32 rows x 32 slots ----
  int ar = tid >> 5, as_ = tid & 31;
  int aw = ar*256 + ((as_ ^ (ar & 7)) << 3);
  const float* ap = x + (rowbase + ar)*256 + as_*8;

  // slab read addrs for ctx (constant), stride 40, no XOR
  int ca0 = h*32 + cl, ca1 = h*32 + 16 + cl;
  int cb  = 256 + h*32 + (isV ? 16 : 0) + cl;
  int ra0 = ca0*40 + fs*8;
  int ra1 = ca1*40 + fs*8;
  int rb  = cb*40  + fs*8;

  // Qs store bases: row m*16+cl, cols w*16+rq..+3
  unsigned short* qsg0 = Qs + (rowbase + cl)*256 + w*16 + rq;
  unsigned short* qsg1 = qsg0 + 16*256;

  f32x4 acc[2][2];
  f32x4 ql0, ql1;                            // q logits (m=0,1)
  float e00, e01, e02, e03, e10, e11, e12, e13;
  float sp0, sp1;

  auto stageA = [&](int buf, float4 v0, float4 v1) {
    unsigned short* Ab = &As[buf][0];
    union { ushort4 u4[2]; int4 i4; } pk;
    pk.u4[0].x = f2bf(v0.x); pk.u4[0].y = f2bf(v0.y); pk.u4[0].z = f2bf(v0.z); pk.u4[0].w = f2bf(v0.w);
    pk.u4[1].x = f2bf(v1.x); pk.u4[1].y = f2bf(v1.y); pk.u4[1].z = f2bf(v1.z); pk.u4[1].w = f2bf(v1.w);
    *(int4*)(&Ab[aw]) = pk.i4;
  };
  auto mainMFMA = [&](int buf) {
    unsigned short* Ab = &As[buf][0];
#pragma unroll
    for (int m = 0; m < 2; ++m)
#pragma unroll
      for (int ni = 0; ni < 2; ++ni) acc[m][ni] = (f32x4){};
    ql0 = (f32x4){}; ql1 = (f32x4){};
#pragma unroll
    for (int kk = 0; kk < 8; ++kk) {
      int so = (((kk*4 + fs) ^ (cl & 7)) << 3);
      bf16x8 a0 = *(const bf16x8*)(&Ab[cl*256 + so]);
      bf16x8 a1 = *(const bf16x8*)(&Ab[(16 + cl)*256 + so]);
#pragma unroll
      for (int ni = 0; ni < 2; ++ni) {
        acc[0][ni] = __builtin_amdgcn_mfma_f32_16x16x32_bf16(a0, bfr[ni][kk], acc[0][ni], 0, 0, 0);
        acc[1][ni] = __builtin_amdgcn_mfma_f32_16x16x32_bf16(a1, bfr[ni][kk], acc[1][ni], 0, 0, 0);
      }
      bf16x8 bqk = *(const bf16x8*)(bqp + kk*32);
      ql0 = __builtin_amdgcn_mfma_f32_16x16x32_bf16(bqk, a0, ql0, 0, 0, 0);
      ql1 = __builtin_amdgcn_mfma_f32_16x16x32_bf16(bqk, a1, ql1, 0, 0, 0);
    }
  };
  auto slabWrite = [&](int buf) {
    unsigned short* sb = &slab[buf][0];
#pragma unroll
    for (int ni = 0; ni < 2; ++ni) {
      int c = w*32 + ni*16 + cl;
#pragma unroll
      for (int m = 0; m < 2; ++m) {
        int n4 = m*16 + rq;
        ushort4 wv;
        if (!isV) {
          float x0 = __expf(acc[m][ni][0]), x1 = __expf(acc[m][ni][1]);
          float x2 = __expf(acc[m][ni][2]), x3 = __expf(acc[m][ni][3]);
          if (ni == 0) dena0 += (x0 + x1) + (x2 + x3); else dena1 += (x0 + x1) + (x2 + x3);
          wv.x = f2bf(x0); wv.y = f2bf(x1); wv.z = f2bf(x2); wv.w = f2bf(x3);
        } else {
          wv.x = f2bf(acc[m][ni][0]); wv.y = f2bf(acc[m][ni][1]);
          wv.z = f2bf(acc[m][ni][2]); wv.w = f2bf(acc[m][ni][3]);
        }
        *(ushort4*)(&sb[c*40 + n4]) = wv;
      }
    }
  };
  auto qExp = [&](int buf) {                 // pre-bar: exp + wave-sum + qsum write
    e00 = __expf(ql0[0]); e01 = __expf(ql0[1]); e02 = __expf(ql0[2]); e03 = __expf(ql0[3]);
    e10 = __expf(ql1[0]); e11 = __expf(ql1[1]); e12 = __expf(ql1[2]); e13 = __expf(ql1[3]);
    sp0 = (e00 + e01) + (e02 + e03);
    sp1 = (e10 + e11) + (e12 + e13);
    sp0 += __shfl_xor(sp0, 16); sp0 += __shfl_xor(sp0, 32);
    sp1 += __shfl_xor(sp1, 16); sp1 += __shfl_xor(sp1, 32);
    if (fs == 0) {
      qsum[buf][w*32 + cl]      = sp0;
      qsum[buf][w*32 + 16 + cl] = sp1;
    }
  };
  auto qFinish = [&](int buf, int t) {       // post-bar: pair-sum, inv, global store
    float t0 = sp0 + qsum[buf][(w ^ 1)*32 + cl];
    float t1 = sp1 + qsum[buf][(w ^ 1)*32 + 16 + cl];
    float i0 = 1.0f / t0, i1 = 1.0f / t1;
    ushort4 u0, u1;
    u0.x = f2bf(e00*i0); u0.y = f2bf(e01*i0); u0.z = f2bf(e02*i0); u0.w = f2bf(e03*i0);
    u1.x = f2bf(e10*i1); u1.y = f2bf(e11*i1); u1.z = f2bf(e12*i1); u1.w = f2bf(e13*i1);
    *(ushort4*)(qsg0 + (size_t)t*8192) = u0;
    *(ushort4*)(qsg1 + (size_t)t*8192) = u1;
  };
  auto ctxMFMA = [&](int buf) {
    unsigned short* sb = &slab[buf][0];
    bf16x8 af0 = *(const bf16x8*)(&sb[ra0]);
    bf16x8 af1 = *(const bf16x8*)(&sb[ra1]);
    bf16x8 bv  = *(const bf16x8*)(&sb[rb]);
    c2[0] = __builtin_amdgcn_mfma_f32_16x16x32_bf16(af0, bv, c2[0], 0, 0, 0);
    c2[1] = __builtin_amdgcn_mfma_f32_16x16x32_bf16(af1, bv, c2[1], 0, 0, 0);
  };

  // ---- prologue: stage strip 0, prefetch strip 1, compute strip 0 ----
  float4 pa0 = *(const float4*)ap;
  float4 pa1 = *(const float4*)(ap + 4);
  stageA(0, pa0, pa1);
  {
    const float* apn = ap + 32*256;
    pa0 = *(const float4*)apn;
    pa1 = *(const float4*)(apn + 4);
  }
  bar_lds();
  mainMFMA(0);

  // ---- main loop: 16 strips ----
  for (int t = 0; t < 15; ++t) {
    slabWrite(t & 1);
    qExp(t & 1);
    stageA((t + 1) & 1, pa0, pa1);
    bar_lds();
    qFinish(t & 1, t);
    if (t < 14) {
      const float* apn = ap + (size_t)(t + 2)*32*256;
      pa0 = *(const float4*)apn;
      pa1 = *(const float4*)(apn + 4);
    }
    ctxMFMA(t & 1);
    mainMFMA((t + 1) & 1);
  }
  // ---- tail: strip 15 ----
  slabWrite(1);
  qExp(1);
  bar_lds();
  qFinish(1, 15);
  ctxMFMA(1);

  // ---- store partials: ctxp[bid][h][d*33 + e], den at e=32 ----
  float* cp = ctxp + ((size_t)bid*8 + h)*1056;
  int ec = isV ? 16 + cl : cl;
#pragma unroll
  for (int di = 0; di < 2; ++di)
#pragma unroll
    for (int r = 0; r < 4; ++r)
      cp[(di*16 + rq + r)*33 + ec] = c2[di][r];
  if (!isV) {
    dena0 += __shfl_xor(dena0, 16); dena0 += __shfl_xor(dena0, 32);
    dena1 += __shfl_xor(dena1, 16); dena1 += __shfl_xor(dena1, 32);
    if (fs == 0) {
      cp[cl*33 + 32]        = dena0;
      cp[(16 + cl)*33 + 32] = dena1;
    }
  }
}

// ---------------- K2b: W2t[bf][c][hd] = sum_e (ctx/den) * Wo ----------------
__global__ __launch_bounds__(256) void k2b_w2(const float* __restrict__ ctxp,
                                              const float* __restrict__ Wo,
                                              unsigned short* __restrict__ W2t) {
  __shared__ float clds[32*33];
  int bid = blockIdx.x;                    // bf*8 + h
  int h = bid & 7, bfi = bid >> 3;
  int tid = threadIdx.x;                   // = c
  for (int i = tid; i < 1056; i += 256) {
    float s = 0.f;
#pragma unroll
    for (int p = 0; p < 8; ++p)            // 8 row-chunks of 512 per bf
      s += ctxp[((size_t)(bfi*8 + p)*8 + h)*1056 + i];
    clds[i] = s;
  }
  __syncthreads();
  float acc[32] = {};
#pragma unroll 4
  for (int e = 0; e < 32; ++e) {
    float w = Wo[(size_t)(h*32 + e)*256 + tid];
#pragma unroll
    for (int d = 0; d < 32; ++d) acc[d] += clds[d*33 + e] * w;
  }
  unsigned short* o = W2t + ((size_t)bfi*256 + tid)*256 + h*32;
#pragma unroll
  for (int d = 0; d < 32; ++d) o[d] = f2bf(acc[d] / clds[d*33 + 32]);
}

// ---------------- K3b: out = Qs @ W2t[bf]^T (pure GEMM) ----------------
// Grid 512 x 512thr, 256 rows/block, 8 strips of 32 rows, 1 lgkm-barrier/strip.
// A staged from Qs bf16 via reg-prefetched int4 (k3n pattern); B panel in regs.
__global__ __launch_bounds__(512, 2) void k3b(const unsigned short* __restrict__ Qs,
                                              const unsigned short* __restrict__ W2t,
                                              float* __restrict__ out) {
  __shared__ unsigned short As[2][32*256];   // 16 KB each, swizzled (32 slots/row)
  int bid = blockIdx.x;
  size_t rowbase = (size_t)bid * 256;
  int bfi = bid >> 4;                        // 16 blocks per bf
  int tid = threadIdx.x;
  int lane = tid & 63, wid = tid >> 6;
  int cl = lane & 15, rq = (lane >> 4) << 2, fs = lane >> 4;

  // ---- B panel in registers ----
  bf16x8 bw[2][8];
#pragma unroll
  for (int nf = 0; nf < 2; ++nf)
#pragma unroll
    for (int kk = 0; kk < 8; ++kk)
      bw[nf][kk] = *(const bf16x8*)(W2t + ((size_t)bfi*256 + wid*32 + nf*16 + cl)*256 + kk*32 + fs*8);

  // ---- staging map: rows sr and 16+sr, slot ss; linear loads, swizzled ds_write ----
  int sr = tid >> 5, ss = tid & 31;
  const unsigned short* xsrc = Qs + (rowbase + sr)*256 + ss*8;
  int aw0 = sr*256 + ((ss ^ (sr & 7)) << 3);
  int aw1 = aw0 + 16*256;                    // (16+sr)&7 == sr&7

  int4 qa, qb;

  // ---- prologue: stage strip 0, prefetch strip 1 ----
  qa = *(const int4*)xsrc;
  qb = *(const int4*)(xsrc + 16*256);
  *(int4*)(&As[0][aw0]) = qa;
  *(int4*)(&As[0][aw1]) = qb;
  qa = *(const int4*)(xsrc + 8192);
  qb = *(const int4*)(xsrc + 8192 + 16*256);
  bar_lds();

  for (int t = 0; t < 8; ++t) {
    // P2(t)
    f32x4 oa[2][2] = {};
    {
      unsigned short* Ab = &As[t & 1][0];
#pragma unroll
      for (int kk = 0; kk < 8; ++kk) {
        int so = (((kk*4 + fs) ^ (cl & 7)) << 3);
        bf16x8 q0 = *(const bf16x8*)(&Ab[cl*256 + so]);
        bf16x8 q1 = *(const bf16x8*)(&Ab[(16 + cl)*256 + so]);
#pragma unroll
        for (int nf = 0; nf < 2; ++nf) {
          oa[0][nf] = __builtin_amdgcn_mfma_f32_16x16x32_bf16(bw[nf][kk], q0, oa[0][nf], 0, 0, 0);
          oa[1][nf] = __builtin_amdgcn_mfma_f32_16x16x32_bf16(bw[nf][kk], q1, oa[1][nf], 0, 0, 0);
        }
      }
    }
    if (t < 7) {
      // stage As(t+1) from regs, prefetch strip t+2; barrier before next P2
      *(int4*)(&As[(t + 1) & 1][aw0]) = qa;
      *(int4*)(&As[(t + 1) & 1][aw1]) = qb;
      if (t < 6) {
        qa = *(const int4*)(xsrc + (size_t)(t + 2)*8192);
        qb = *(const int4*)(xsrc + (size_t)(t + 2)*8192 + 16*256);
      }
      bar_lds();
    }
    // out(t): float4 stores (stay in flight)
#pragma unroll
    for (int m = 0; m < 2; ++m)
#pragma unroll
      for (int nf = 0; nf < 2; ++nf)
        *(f32x4*)(&out[(rowbase + (size_t)t*32 + m*16 + cl)*256 + wid*32 + nf*16 + rq]) = oa[m][nf];
  }
}

extern "C" void kernel_launch(void* const* d_in, const int* in_sizes, int n_in,
                              void* d_out, int out_size, void* d_ws, size_t ws_size,
                              hipStream_t stream) {
  const float* x  = (const float*)d_in[0];
  const float* Wq = (const float*)d_in[1];
  const float* Wk = (const float*)d_in[2];
  const float* Wv = (const float*)d_in[3];
  const float* Wo = (const float*)d_in[4];
  float* out = (float*)d_out;

  // ws layout: WkvT (131072 ush) | WqT (65536 ush) | W2t (2097152 ush)
  //          | ctxp (256*8*1056 f32) | Qs (131072*256 ush, softmaxed q bf16)
  unsigned short* WkvT = (unsigned short*)d_ws;
  unsigned short* WqT  = WkvT + 131072;
  unsigned short* W2t  = WqT  + 65536;
  float*          ctxp = (float*)(W2t + 2097152);
  unsigned short* Qs   = (unsigned short*)(ctxp + (size_t)256*8*1056);

  k0_prep <<<768,  256,  0, stream>>>(Wq, Wk, Wv, WqT, WkvT);
  k1q     <<<256,  1024, 0, stream>>>(x, WkvT, WqT, ctxp, Qs);
  k2b_w2  <<<256,  256,  0, stream>>>(ctxp, Wo, W2t);
  k3b     <<<512,  512,  0, stream>>>(Qs, W2t, out);
}